// Round 2
// baseline (262.011 us; speedup 1.0000x reference)
//
#include <hip/hip_runtime.h>

// out[p][j] = L(j-1) - L(j), L(e) = relu(1 - relu(x_full[e+1]-x)/(h[e]+1e-9)),
// L(-1)=1, L(n_elem)=0. Monotone staircase => each row is zero except
//   out[e0] = 1-frac, out[e0+1] = frac   (e0 = interval containing x, clamped).
//
// Round-2 strategy: single fused kernel writes the entire 268.6 MB output once
// with coalesced float4 stores (no memset + scatter RMW, one dispatch).
// Rows are 2049 floats (8196 B, only 4-B aligned), but 4 rows = 16*n_nodes B:
// always 16-B aligned and exactly n_nodes float4s -> block per 4-row group.

__global__ __launch_bounds__(256) void fused_rows4(
        const float* __restrict__ x_eval,
        const float* __restrict__ x_full,
        float* __restrict__ out,
        int n_points, int n_nodes) {
    __shared__ int   s_e0[4];
    __shared__ float s_a[4], s_b[4];

    const int p0 = blockIdx.x * 4;

    if (threadIdx.x < 4) {
        int p = p0 + threadIdx.x;
        float x = x_eval[p];
        // upper_bound: first idx with x_full[idx] > x
        int lo = 0, hi = n_nodes;
        while (lo < hi) {
            int mid = (lo + hi) >> 1;
            if (x_full[mid] <= x) lo = mid + 1; else hi = mid;
        }
        int e0 = lo - 1;
        if (e0 < 0) e0 = 0;
        int emax = n_nodes - 2;
        if (e0 > emax) e0 = emax;
        float xa = x_full[e0];
        float xb = x_full[e0 + 1];
        float l1   = fmaxf(xb - x, 0.0f);
        float frac = fmaxf(1.0f - l1 / (xb - xa + 1e-9f), 0.0f);
        s_e0[threadIdx.x] = e0;
        s_a[threadIdx.x]  = 1.0f - frac;
        s_b[threadIdx.x]  = frac;
    }
    __syncthreads();

    // Block-uniform params into registers.
    const int   e00 = s_e0[0], e01 = s_e0[1], e02 = s_e0[2], e03 = s_e0[3];
    const float a0 = s_a[0], a1 = s_a[1], a2 = s_a[2], a3 = s_a[3];
    const float b0 = s_b[0], b1 = s_b[1], b2 = s_b[2], b3 = s_b[3];
    const int n1 = n_nodes, n2 = 2 * n_nodes, n3 = 3 * n_nodes;
    // Flat (within 4-row group) indices of the two nonzeros per row.
    const int t0 = e00, t1 = n1 + e01, t2 = n2 + e02, t3 = n3 + e03;

    float4* obase = (float4*)(out + (size_t)p0 * (size_t)n_nodes);
    // 4 rows = 4*n_nodes floats = exactly n_nodes float4s, 16-B aligned.
    for (int q = threadIdx.x; q < n_nodes; q += 256) {
        const int f0 = q << 2;
        float v[4];
#pragma unroll
        for (int k = 0; k < 4; ++k) {
            const int f = f0 + k;
            float v0 = 0.0f;
            v0 = (f == t0)     ? a0 : v0;
            v0 = (f == t0 + 1) ? b0 : v0;
            v0 = (f == t1)     ? a1 : v0;
            v0 = (f == t1 + 1) ? b1 : v0;
            v0 = (f == t2)     ? a2 : v0;
            v0 = (f == t2 + 1) ? b2 : v0;
            v0 = (f == t3)     ? a3 : v0;
            v0 = (f == t3 + 1) ? b3 : v0;
            v[k] = v0;
        }
        obase[q] = make_float4(v[0], v[1], v[2], v[3]);
    }
}

// Fallback path (n_points not divisible by 4): memset + scatter, as round 1.
__global__ void scatter_hats(const float* __restrict__ x_eval,
                             const float* __restrict__ x_full,
                             float* __restrict__ out,
                             int n_points, int n_nodes) {
    extern __shared__ float s_xf[];
    for (int i = threadIdx.x; i < n_nodes; i += blockDim.x) s_xf[i] = x_full[i];
    __syncthreads();
    int p = blockIdx.x * blockDim.x + threadIdx.x;
    if (p >= n_points) return;
    float x = x_eval[p];
    int lo = 0, hi = n_nodes;
    while (lo < hi) {
        int mid = (lo + hi) >> 1;
        if (s_xf[mid] <= x) lo = mid + 1; else hi = mid;
    }
    int e0 = lo - 1;
    if (e0 < 0) e0 = 0;
    int emax = n_nodes - 2;
    if (e0 > emax) e0 = emax;
    float xa = s_xf[e0];
    float xb = s_xf[e0 + 1];
    float l1   = fmaxf(xb - x, 0.0f);
    float frac = fmaxf(1.0f - l1 / (xb - xa + 1e-9f), 0.0f);
    size_t base = (size_t)p * (size_t)n_nodes;
    out[base + e0]     = 1.0f - frac;
    out[base + e0 + 1] = frac;
}

extern "C" void kernel_launch(void* const* d_in, const int* in_sizes, int n_in,
                              void* d_out, int out_size, void* d_ws, size_t ws_size,
                              hipStream_t stream) {
    const float* x_eval = (const float*)d_in[0];
    const float* x_full = (const float*)d_in[1];
    float* out = (float*)d_out;

    int n_points = in_sizes[0];   // 32768
    int n_nodes  = in_sizes[1];   // 2049 (= output columns)

    if ((n_points % 4) == 0 && n_nodes >= 2) {
        int grid = n_points / 4;  // one block per 4-row group
        fused_rows4<<<grid, 256, 0, stream>>>(x_eval, x_full, out, n_points, n_nodes);
    } else {
        hipMemsetAsync(d_out, 0, (size_t)out_size * sizeof(float), stream);
        int block = 256;
        int grid  = (n_points + block - 1) / block;
        size_t smem = (size_t)n_nodes * sizeof(float);
        scatter_hats<<<grid, block, smem, stream>>>(x_eval, x_full, out, n_points, n_nodes);
    }
}

// Round 3
// 260.350 us; speedup vs baseline: 1.0064x; 1.0064x over previous
//
#include <hip/hip_runtime.h>

// out[p][j] = L(j-1) - L(j), L(e) = relu(1 - relu(x_full[e+1]-x)/(h[e]+1e-9)),
// L(-1)=1, L(n_elem)=0. Monotone staircase => each row is zero except
//   out[e0] = 1-frac, out[e0+1] = frac   (e0 = interval containing x, clamped).
//
// Single-pass kernel: block per 4-row group (4 rows = 16*n_nodes B -> 16-B
// aligned, exact float4 count). Hot loop stores zero float4s branch-free;
// the select chain only runs for the ~2 float4s per row that straddle the
// transition (t_k in [f0-1, f0+3]).

__global__ __launch_bounds__(256) void fused_rows4(
        const float* __restrict__ x_eval,
        const float* __restrict__ x_full,
        float* __restrict__ out,
        int n_points, int n_nodes) {
    __shared__ int   s_e0[4];
    __shared__ float s_a[4], s_b[4];

    const int p0 = blockIdx.x * 4;

    if (threadIdx.x < 4) {
        int p = p0 + threadIdx.x;
        float x = x_eval[p];
        int lo = 0, hi = n_nodes;          // upper_bound
        while (lo < hi) {
            int mid = (lo + hi) >> 1;
            if (x_full[mid] <= x) lo = mid + 1; else hi = mid;
        }
        int e0 = lo - 1;
        if (e0 < 0) e0 = 0;
        int emax = n_nodes - 2;
        if (e0 > emax) e0 = emax;
        float xa = x_full[e0];
        float xb = x_full[e0 + 1];
        float l1   = fmaxf(xb - x, 0.0f);
        float frac = fmaxf(1.0f - l1 / (xb - xa + 1e-9f), 0.0f);
        s_e0[threadIdx.x] = e0;
        s_a[threadIdx.x]  = 1.0f - frac;
        s_b[threadIdx.x]  = frac;
    }
    __syncthreads();

    const float a0 = s_a[0], a1 = s_a[1], a2 = s_a[2], a3 = s_a[3];
    const float b0 = s_b[0], b1 = s_b[1], b2 = s_b[2], b3 = s_b[3];
    // Flat (within 4-row group) indices of each row's first nonzero.
    const int t0 = s_e0[0];
    const int t1 = n_nodes     + s_e0[1];
    const int t2 = 2 * n_nodes + s_e0[2];
    const int t3 = 3 * n_nodes + s_e0[3];

    float4* obase = (float4*)(out + (size_t)p0 * (size_t)n_nodes);
    const int nq = n_nodes;   // 4 rows = exactly n_nodes float4s
    const float4 zero4 = make_float4(0.0f, 0.0f, 0.0f, 0.0f);

#pragma unroll 4
    for (int q = threadIdx.x; q < nq; q += 256) {
        const int f0 = q << 2;
        float4 v = zero4;
        // float4 covers flat [f0, f0+3]; row k contributes iff t_k in [f0-1, f0+3].
        const bool h0 = (unsigned)(t0 - f0 + 1) <= 4u;
        const bool h1 = (unsigned)(t1 - f0 + 1) <= 4u;
        const bool h2 = (unsigned)(t2 - f0 + 1) <= 4u;
        const bool h3 = (unsigned)(t3 - f0 + 1) <= 4u;
        if (h0 | h1 | h2 | h3) {          // rare: ~8 of 2049 iterations/block
            float vv[4];
#pragma unroll
            for (int k = 0; k < 4; ++k) {
                const int f = f0 + k;
                float v0 = 0.0f;
                v0 = (f == t0)     ? a0 : v0;
                v0 = (f == t0 + 1) ? b0 : v0;
                v0 = (f == t1)     ? a1 : v0;
                v0 = (f == t1 + 1) ? b1 : v0;
                v0 = (f == t2)     ? a2 : v0;
                v0 = (f == t2 + 1) ? b2 : v0;
                v0 = (f == t3)     ? a3 : v0;
                v0 = (f == t3 + 1) ? b3 : v0;
                vv[k] = v0;
            }
            v = make_float4(vv[0], vv[1], vv[2], vv[3]);
        }
        obase[q] = v;
    }
}

// Fallback (n_points not divisible by 4): memset + scatter.
__global__ void scatter_hats(const float* __restrict__ x_eval,
                             const float* __restrict__ x_full,
                             float* __restrict__ out,
                             int n_points, int n_nodes) {
    extern __shared__ float s_xf[];
    for (int i = threadIdx.x; i < n_nodes; i += blockDim.x) s_xf[i] = x_full[i];
    __syncthreads();
    int p = blockIdx.x * blockDim.x + threadIdx.x;
    if (p >= n_points) return;
    float x = x_eval[p];
    int lo = 0, hi = n_nodes;
    while (lo < hi) {
        int mid = (lo + hi) >> 1;
        if (s_xf[mid] <= x) lo = mid + 1; else hi = mid;
    }
    int e0 = lo - 1;
    if (e0 < 0) e0 = 0;
    int emax = n_nodes - 2;
    if (e0 > emax) e0 = emax;
    float xa = s_xf[e0];
    float xb = s_xf[e0 + 1];
    float l1   = fmaxf(xb - x, 0.0f);
    float frac = fmaxf(1.0f - l1 / (xb - xa + 1e-9f), 0.0f);
    size_t base = (size_t)p * (size_t)n_nodes;
    out[base + e0]     = 1.0f - frac;
    out[base + e0 + 1] = frac;
}

extern "C" void kernel_launch(void* const* d_in, const int* in_sizes, int n_in,
                              void* d_out, int out_size, void* d_ws, size_t ws_size,
                              hipStream_t stream) {
    const float* x_eval = (const float*)d_in[0];
    const float* x_full = (const float*)d_in[1];
    float* out = (float*)d_out;

    int n_points = in_sizes[0];   // 32768
    int n_nodes  = in_sizes[1];   // 2049 (= output columns)

    if ((n_points % 4) == 0 && n_nodes >= 2) {
        int grid = n_points / 4;  // one block per 4-row group
        fused_rows4<<<grid, 256, 0, stream>>>(x_eval, x_full, out, n_points, n_nodes);
    } else {
        hipMemsetAsync(d_out, 0, (size_t)out_size * sizeof(float), stream);
        int block = 256;
        int grid  = (n_points + block - 1) / block;
        size_t smem = (size_t)n_nodes * sizeof(float);
        scatter_hats<<<grid, block, smem, stream>>>(x_eval, x_full, out, n_points, n_nodes);
    }
}